// Round 13
// baseline (185.736 us; speedup 1.0000x reference)
//
#include <hip/hip_runtime.h>

// GGNN on MI355X. N=100000, E=1000000, H=M=64, C=16.
// R6: deterministic bucket sort (hist / scan / place / gather / MFMA GRU).
// R9/R10: GRU weights in LDS. R11: fused k_gm. R15: fvv spill fix -> 61-62us.
// R16/R17/R18: VALU cut neutral, LDS-atomic disaster, 4-edge unroll +1us ->
//      three near-neutral rounds on the "TLP-curable latency" theory, and
//      R9->R10 showed 2x residency bought only 5%. Stop guessing: ABLATE.
// R19: split k_gm -> k_g2 + k_m2, each with its own counters and occupancy:
//      k_g2 (csr+gather+convert, 25.6KB LDS -> 4 blocks/CU = 32 waves):
//        clean test of TLP theory with 2x the waves. R18 4-edge unroll.
//        Stores AS1/AS0 bf16 (bit-identical to fused in-reg conversion).
//      k_m2 (AS load + wlds + agg/GRU/out): R10 structure + R15 fvb fix.
//      Pre-registered: k_g2 fast (15-22us, occ>50%) => TLP works, keep;
//      k_g2 ~30us at high occ => per-CU serial resource, change attack.
//      absmax must stay 0.0078125 exactly.
// ws: [featb | region 782*1600 | hist 245*782 | blockBase 245*782 |
//      bucketCnt 782 | cc N | s1b | s0b | wb | flag]

typedef __bf16 bf16x8 __attribute__((ext_vector_type(8)));
typedef float  f32x4  __attribute__((ext_vector_type(4)));
typedef int    i32x4  __attribute__((ext_vector_type(4)));

#define MFMA16 __builtin_amdgcn_mfma_f32_16x16x32_bf16
#define NN   100000
#define EE   1000000
#define BB   782     // buckets (dst >> 7)
#define NPB  128     // nodes per bucket
#define ECAP 1600    // bucket region capacity (mean 1280, +9 sigma)
#define DCAP 48      // per-node degree cap (Poisson(10), P(>=48) ~ 1e-17)
#define CSTRD 49     // CSR LDS stride (conflict pad)
#define NB   245     // histogram blocks (4096 edges each)
#define NWL  24576   // LDS-staged weights: wih (12288) + whh (12288)

__device__ __forceinline__ float sigmoidf_(float x) {
    return 1.0f / (1.0f + __expf(-x));
}

// swizzled LDS weight fragment read: e = element offset (16B-aligned).
__device__ __forceinline__ bf16x8 ldw(const __bf16* w, int e) {
    int bo = e * 2;
    bo ^= ((bo >> 7) & 7) << 4;
    return *(const bf16x8*)((const char*)w + bo);
}

// ---- fused init: dtype detect / weight cvt / feature cvt / dst histogram ----
__global__ __launch_bounds__(256) void k_init(const unsigned char* __restrict__ et,
                                              const float* __restrict__ feat,
                                              const int* __restrict__ dst,
                                              const float* __restrict__ w0,
                                              const float* __restrict__ w1,
                                              const float* __restrict__ wih,
                                              const float* __restrict__ whh,
                                              const float* __restrict__ wout,
                                              __bf16* __restrict__ featb,
                                              __bf16* __restrict__ wb,
                                              int* __restrict__ hist,
                                              int* __restrict__ flag) {
    int b = blockIdx.x, tid = threadIdx.x;
    if (b == 0) {
        // flag=1 iff any nonzero byte at offset%4!=0 in first 64KB (bool
        // storage); int32 0/1 storage has bytes 1..3 of every word zero.
        __shared__ int sdet[4];
        const i32x4* p = (const i32x4*)et + tid * 16;  // 256 B per thread
        unsigned acc = 0;
#pragma unroll
        for (int j = 0; j < 16; j++) {
            i32x4 w = p[j];
            acc |= (unsigned)(w[0] | w[1] | w[2] | w[3]) & 0xffffff00u;
        }
        unsigned long long m = __ballot(acc != 0);
        if ((tid & 63) == 0) sdet[tid >> 6] = (m != 0ULL);
        __syncthreads();
        if (tid == 0) *flag = sdet[0] | sdet[1] | sdet[2] | sdet[3];
        return;
    }
    if (b < 133) {  // 132 blocks * 256 = 33792 weights exactly
        int i = (b - 1) * 256 + tid;
        float v;
        if      (i < 4096)  v = w0[i];
        else if (i < 8192)  v = w1[i - 4096];
        else if (i < 20480) v = wih[i - 8192];
        else if (i < 32768) v = whh[i - 20480];
        else                v = wout[i - 32768];
        wb[i] = (__bf16)v;
        return;
    }
    if (b >= 6383) {  // fused k_s1: per-block dst-bucket histogram
        __shared__ int cnt[BB];
        int hb = b - 6383;
        for (int i = tid; i < BB; i += 256) cnt[i] = 0;
        __syncthreads();
        long e0 = (long)hb * 4096 + tid * 16;
#pragma unroll
        for (int g = 0; g < 2; g++) {
            long e = e0 + g * 8;
            if (e < EE) {
                i32x4 d0 = *(const i32x4*)(dst + e);
                i32x4 d1 = *(const i32x4*)(dst + e + 4);
#pragma unroll
                for (int j = 0; j < 4; j++) atomicAdd(&cnt[d0[j] >> 7], 1);
#pragma unroll
                for (int j = 0; j < 4; j++) atomicAdd(&cnt[d1[j] >> 7], 1);
            }
        }
        __syncthreads();
        for (int i = tid; i < BB; i += 256) hist[hb * BB + i] = cnt[i];
        return;
    }
    long i = ((long)(b - 133) * 256 + tid) * 4;
    if (i >= (long)NN * 64) return;
    f32x4 v = *(const f32x4*)(feat + i);
    union { __bf16 e[4]; unsigned long long u; } o;
#pragma unroll
    for (int j = 0; j < 4; j++) o.e[j] = (__bf16)v[j];
    *(unsigned long long*)(featb + i) = o.u;
}

// ---- s2: exclusive scan over blocks per bucket (1 wave/bucket) ----
__global__ __launch_bounds__(256) void k_s2(const int* __restrict__ hist,
                                            int* __restrict__ blockBase,
                                            int* __restrict__ bucketCnt) {
    int b = blockIdx.x * 4 + (threadIdx.x >> 6);
    int lane = threadIdx.x & 63;
    if (b >= BB) return;
    int carry = 0;
    for (int c = 0; c < 4; c++) {       // ceil(245/64) = 4 chunks
        int blk = c * 64 + lane;
        int v = (blk < NB) ? hist[blk * BB + b] : 0;
        int x = v;
#pragma unroll
        for (int off = 1; off < 64; off <<= 1) {
            int y = __shfl_up(x, off, 64);
            if (lane >= off) x += y;
        }
        if (blk < NB) blockBase[blk * BB + b] = x - v + carry;
        carry += __shfl(x, 63, 64);
    }
    if (lane == 0) bucketCnt[b] = carry;
}

// ---- s3: place edges deterministically (LDS cursors seeded w/ blockBase) ----
__global__ __launch_bounds__(512) void k_s3(const int* __restrict__ src,
                                            const int* __restrict__ dst,
                                            const unsigned char* __restrict__ etype,
                                            const int* __restrict__ flag,
                                            const int* __restrict__ blockBase,
                                            int* __restrict__ region) {
    __shared__ int cur[BB];
    int blk = blockIdx.x, tid = threadIdx.x;
    for (int i = tid; i < BB; i += 512) cur[i] = blockBase[blk * BB + i];
    __syncthreads();
    long e0 = (long)blk * 4096 + tid * 8;
    if (e0 >= EE) return;
    i32x4 s0 = *(const i32x4*)(src + e0);
    i32x4 s1 = *(const i32x4*)(src + e0 + 4);
    i32x4 d0 = *(const i32x4*)(dst + e0);
    i32x4 d1 = *(const i32x4*)(dst + e0 + 4);
    int t[8];
    if (*flag) {  // 1-byte bool storage
        unsigned long long w = *(const unsigned long long*)(etype + e0);
#pragma unroll
        for (int j = 0; j < 8; j++) t[j] = (int)((w >> (8 * j)) & 0xff);
    } else {      // int32 storage
        i32x4 w0 = *(const i32x4*)((const int*)etype + e0);
        i32x4 w1 = *(const i32x4*)((const int*)etype + e0 + 4);
#pragma unroll
        for (int j = 0; j < 4; j++) { t[j] = w0[j]; t[4 + j] = w1[j]; }
    }
    int dd[8] = {d0[0], d0[1], d0[2], d0[3], d1[0], d1[1], d1[2], d1[3]};
    int ss[8] = {s0[0], s0[1], s0[2], s0[3], s1[0], s1[1], s1[2], s1[3]};
#pragma unroll
    for (int j = 0; j < 8; j++) {
        int b  = dd[j] >> 7;
        int nl = dd[j] & 127;
        int r  = atomicAdd(&cur[b], 1);  // LDS returning atomic: fast
        if (r < ECAP)
            region[b * ECAP + r] = (nl << 18) | ((t[j] ? 1 : 0) << 17) | ss[j];
    }
}

// ---- g2: CSR build + gather (4-edge unroll) + bf16 convert + store ----
// 25.6KB LDS -> 4 blocks/CU (thread-capped, 32 waves): the clean TLP test.
__global__ __launch_bounds__(512) void k_g2(const __bf16* __restrict__ featb,
                                            const int* __restrict__ region,
                                            const int* __restrict__ bucketCnt,
                                            __bf16* __restrict__ s1b,
                                            __bf16* __restrict__ s0b,
                                            int* __restrict__ cc) {
    __shared__ __align__(16) int csr[NPB * CSTRD];
    __shared__ int ncnt[NPB];
    int b = blockIdx.x, tid = threadIdx.x, lane = tid & 63, wave = tid >> 6;
    int L = lane & 15, q = lane >> 4;
    int n0 = b * NPB + wave * 16;

    int cntE = min(bucketCnt[b], ECAP);
    if (tid < NPB) ncnt[tid] = 0;
    __syncthreads();
    const int* reg = region + b * ECAP;
    for (int i = tid; i < cntE; i += 512) {
        int rec = reg[i];
        int nl = rec >> 18;
        int r = atomicAdd(&ncnt[nl], 1);
        if (r < DCAP) csr[nl * CSTRD + r] = rec & 0x3ffff;  // type|src
    }
    __syncthreads();

    int nl = wave * 16 + L;
    int cnt = (n0 < NN) ? min(ncnt[nl], DCAP) : 0;
    const int* eb = &csr[nl * CSTRD];

    float sA[16], s1[16];
#pragma unroll
    for (int j = 0; j < 16; j++) { sA[j] = 0.f; s1[j] = 0.f; }
    int c1 = 0;
    int i = 0;
    for (; i + 4 <= cnt; i += 4) {  // R18 4-edge unroll: 8 loads in flight
        int e0v = eb[i], e1v = eb[i + 1], e2v = eb[i + 2], e3v = eb[i + 3];
        const __bf16* r0 = featb + (long)(e0v & 0x1ffff) * 64;
        const __bf16* r1 = featb + (long)(e1v & 0x1ffff) * 64;
        const __bf16* r2 = featb + (long)(e2v & 0x1ffff) * 64;
        const __bf16* r3 = featb + (long)(e3v & 0x1ffff) * 64;
        bf16x8 a0 = *(const bf16x8*)(r0 + q * 8);
        bf16x8 a1 = *(const bf16x8*)(r0 + 32 + q * 8);
        bf16x8 b0v = *(const bf16x8*)(r1 + q * 8);
        bf16x8 b1v = *(const bf16x8*)(r1 + 32 + q * 8);
        bf16x8 c0v = *(const bf16x8*)(r2 + q * 8);
        bf16x8 c1v = *(const bf16x8*)(r2 + 32 + q * 8);
        bf16x8 d0v = *(const bf16x8*)(r3 + q * 8);
        bf16x8 d1v = *(const bf16x8*)(r3 + 32 + q * 8);
        int t0 = (e0v >> 17) & 1, t1 = (e1v >> 17) & 1;
        int t2 = (e2v >> 17) & 1, t3 = (e3v >> 17) & 1;
        c1 += t0 + t1 + t2 + t3;
        float f0 = (float)t0, f1 = (float)t1, f2 = (float)t2, f3 = (float)t3;
#pragma unroll
        for (int j = 0; j < 8; j++) {
            float va = (float)a0[j], wa = (float)a1[j];
            float vb = (float)b0v[j], wb2 = (float)b1v[j];
            sA[j]     += va + vb;
            sA[8 + j] += wa + wb2;
            s1[j]     += f0 * va + f1 * vb;
            s1[8 + j] += f0 * wa + f1 * wb2;
            float vc = (float)c0v[j], wc = (float)c1v[j];
            float vd = (float)d0v[j], wd = (float)d1v[j];
            sA[j]     += vc + vd;
            sA[8 + j] += wc + wd;
            s1[j]     += f2 * vc + f3 * vd;
            s1[8 + j] += f2 * wc + f3 * wd;
        }
    }
    if (i + 2 <= cnt) {  // 2-edge tail
        int ea = eb[i], ebn = eb[i + 1];
        const __bf16* rowa = featb + (long)(ea & 0x1ffff) * 64;
        const __bf16* rowb = featb + (long)(ebn & 0x1ffff) * 64;
        bf16x8 a0 = *(const bf16x8*)(rowa + q * 8);
        bf16x8 a1 = *(const bf16x8*)(rowa + 32 + q * 8);
        bf16x8 b0v = *(const bf16x8*)(rowb + q * 8);
        bf16x8 b1v = *(const bf16x8*)(rowb + 32 + q * 8);
        int ta = (ea >> 17) & 1, tb = (ebn >> 17) & 1;
        c1 += ta + tb;
        float fa = (float)ta, fb = (float)tb;
#pragma unroll
        for (int j = 0; j < 8; j++) {
            float va = (float)a0[j], wa = (float)a1[j];
            float vb = (float)b0v[j], wb2 = (float)b1v[j];
            sA[j]     += va + vb;
            sA[8 + j] += wa + wb2;
            s1[j]     += fa * va + fb * vb;
            s1[8 + j] += fa * wa + fb * wb2;
        }
        i += 2;
    }
    if (i < cnt) {       // 1-edge tail
        int ea = eb[i];
        const __bf16* rowa = featb + (long)(ea & 0x1ffff) * 64;
        bf16x8 a0 = *(const bf16x8*)(rowa + q * 8);
        bf16x8 a1 = *(const bf16x8*)(rowa + 32 + q * 8);
        int ta = (ea >> 17) & 1;
        c1 += ta;
        float fa = (float)ta;
#pragma unroll
        for (int j = 0; j < 8; j++) {
            float va = (float)a0[j], wa = (float)a1[j];
            sA[j] += va;          sA[8 + j] += wa;
            s1[j] += fa * va;     s1[8 + j] += fa * wa;
        }
    }
    if (n0 >= NN) return;   // after last barrier: safe

    // convert + coalesced 16B stores (bit-identical to fused in-reg path)
    int n = n0 + L;
    union { bf16x8 v; __bf16 e[8]; } u;
#pragma unroll
    for (int ch = 0; ch < 2; ch++) {
#pragma unroll
        for (int j = 0; j < 8; j++) u.e[j] = (__bf16)s1[ch * 8 + j];
        *(bf16x8*)(s1b + (long)n * 64 + ch * 32 + q * 8) = u.v;
#pragma unroll
        for (int j = 0; j < 8; j++) u.e[j] = (__bf16)(sA[ch * 8 + j] - s1[ch * 8 + j]);
        *(bf16x8*)(s0b + (long)n * 64 + ch * 32 + q * 8) = u.v;
    }
    if (q == 0) cc[n] = cnt | (c1 << 16);
}

// ---- m2: AS load + wlds staging + agg MFMA + GRU + classifier ----
// R10 structure (WRITE was clean 6250 there) + R15 fvb-per-nb.
__global__ __launch_bounds__(512, 4) void k_m2(const __bf16* __restrict__ s1b,
                                               const __bf16* __restrict__ s0b,
                                               const __bf16* __restrict__ featb,
                                               const float* __restrict__ feat,
                                               const int* __restrict__ cc,
                                               const __bf16* __restrict__ wb,
                                               const float* __restrict__ b0,
                                               const float* __restrict__ b1,
                                               const float* __restrict__ bih,
                                               const float* __restrict__ bhh,
                                               const float* __restrict__ bout,
                                               float* __restrict__ out) {
    __shared__ __align__(16) __bf16 wlds[NWL];
    __shared__ __align__(16) __bf16 sHall[8][16 * 80];
    int tid = threadIdx.x, lane = tid & 63, wave = tid >> 6;
    int L = lane & 15, q = lane >> 4;
    int n0 = blockIdx.x * NPB + wave * 16;

    // fire-and-forget loads: complete under the staging phase
    bf16x8 AS1[2], AS0[2], Aft[2];
    float fc1[4], fc0[4];
    if (n0 < NN) {
        const __bf16* r1 = s1b + (long)(n0 + L) * 64;
        const __bf16* r0 = s0b + (long)(n0 + L) * 64;
        const __bf16* fr = featb + (long)(n0 + L) * 64;
        AS1[0] = *(const bf16x8*)(r1 + q * 8);  AS1[1] = *(const bf16x8*)(r1 + 32 + q * 8);
        AS0[0] = *(const bf16x8*)(r0 + q * 8);  AS0[1] = *(const bf16x8*)(r0 + 32 + q * 8);
        Aft[0] = *(const bf16x8*)(fr + q * 8);  Aft[1] = *(const bf16x8*)(fr + 32 + q * 8);
        i32x4 cv = *(const i32x4*)(cc + n0 + q * 4);
#pragma unroll
        for (int r = 0; r < 4; r++) {
            int c1 = cv[r] >> 16, ct = cv[r] & 0xffff;
            fc1[r] = (float)c1; fc0[r] = (float)(ct - c1);
        }
    }

    // cooperative GRU-weight staging: 24576 bf16, swizzled 16B blocks
    const __bf16* wsrc = wb + 8192;  // wih | whh
    for (int k = tid * 8; k < NWL; k += 512 * 8) {
        bf16x8 v = *(const bf16x8*)(wsrc + k);
        int bo = k * 2;
        int so = bo ^ (((bo >> 7) & 7) << 4);
        *(bf16x8*)((char*)wlds + so) = v;
    }
    __syncthreads();
    if (n0 >= NN) return;

    __bf16* sH = sHall[wave];
    const __bf16* w0b = wb, * w1b = wb + 4096, * woutb = wb + 32768;
    f32x4 zz = {0.f, 0.f, 0.f, 0.f};

    // agg = S1@W0^T + S0@W1^T + per-count biases (B frags global, L2-hit)
#pragma unroll
    for (int nb = 0; nb < 4; nb++) {
        f32x4 acc = zz;
#pragma unroll
        for (int ch = 0; ch < 2; ch++) {
            int off = (nb * 16 + L) * 64 + ch * 32 + q * 8;
            acc = MFMA16(AS1[ch], *(const bf16x8*)(w0b + off), acc, 0, 0, 0);
            acc = MFMA16(AS0[ch], *(const bf16x8*)(w1b + off), acc, 0, 0, 0);
        }
        float bs0 = b0[nb * 16 + L], bs1 = b1[nb * 16 + L];
#pragma unroll
        for (int r = 0; r < 4; r++)
            sH[(q * 4 + r) * 80 + nb * 16 + L] =
                (__bf16)(acc[r] + fc1[r] * bs0 + fc0[r] * bs1);
    }

    // D->A transpose read (agg region of sH dead after this)
    bf16x8 Aag[2];
#pragma unroll
    for (int ch = 0; ch < 2; ch++)
        Aag[ch] = *(const bf16x8*)&sH[L * 80 + ch * 32 + q * 8];

    // GRU gates [r,z,n]; B fragments from LDS (wih @0, whh @12288).
    // feat fp32 blend values loaded per-nb (4-reg live range, R15).
#pragma unroll
    for (int nb = 0; nb < 4; nb++) {
        int row = nb * 16 + L;
        float fvb[4];
#pragma unroll
        for (int r = 0; r < 4; r++)
            fvb[r] = feat[(long)(n0 + q * 4 + r) * 64 + nb * 16 + L];
        f32x4 aR = zz, aZ = zz, aIN = zz, aHN = zz;
#pragma unroll
        for (int ch = 0; ch < 2; ch++) {
            int ko = ch * 32 + q * 8;
            aR  = MFMA16(Aag[ch], ldw(wlds, row * 64 + ko), aR, 0, 0, 0);
            aR  = MFMA16(Aft[ch], ldw(wlds, 12288 + row * 64 + ko), aR, 0, 0, 0);
            aZ  = MFMA16(Aag[ch], ldw(wlds, (64 + row) * 64 + ko), aZ, 0, 0, 0);
            aZ  = MFMA16(Aft[ch], ldw(wlds, 12288 + (64 + row) * 64 + ko), aZ, 0, 0, 0);
            aIN = MFMA16(Aag[ch], ldw(wlds, (128 + row) * 64 + ko), aIN, 0, 0, 0);
            aHN = MFMA16(Aft[ch], ldw(wlds, 12288 + (128 + row) * 64 + ko), aHN, 0, 0, 0);
        }
        int h = row;
        float br  = bih[h] + bhh[h];
        float bz  = bih[64 + h] + bhh[64 + h];
        float bin = bih[128 + h];
        float bhn = bhh[128 + h];
#pragma unroll
        for (int r = 0; r < 4; r++) {
            float rv = sigmoidf_(aR[r] + br);
            float zv = sigmoidf_(aZ[r] + bz);
            float nv = tanhf(aIN[r] + bin + rv * (aHN[r] + bhn));
            float fv = fvb[r];  // fp32 blend for accuracy
            sH[(q * 4 + r) * 80 + h] = (__bf16)((1.0f - zv) * nv + zv * fv);
        }
    }

    // out = h @ W_out^T + b_out (wout global, L2-hit; store coalesced)
    bf16x8 Ah0 = *(const bf16x8*)&sH[L * 80 + q * 8];
    bf16x8 Ah1 = *(const bf16x8*)&sH[L * 80 + 32 + q * 8];
    bf16x8 Bo0 = *(const bf16x8*)(woutb + L * 64 + q * 8);
    bf16x8 Bo1 = *(const bf16x8*)(woutb + L * 64 + 32 + q * 8);
    f32x4 o = zz;
    o = MFMA16(Ah0, Bo0, o, 0, 0, 0);
    o = MFMA16(Ah1, Bo1, o, 0, 0, 0);
    float bo = bout[L];
#pragma unroll
    for (int r = 0; r < 4; r++)
        out[(long)(n0 + q * 4 + r) * 16 + L] = o[r] + bo;
}

extern "C" void kernel_launch(void* const* d_in, const int* in_sizes, int n_in,
                              void* d_out, int out_size, void* d_ws, size_t ws_size,
                              hipStream_t stream) {
    const float* features = (const float*)d_in[0];
    const int*   src      = (const int*)d_in[1];
    const int*   dst      = (const int*)d_in[2];
    const unsigned char* etype = (const unsigned char*)d_in[3];
    const float* W0   = (const float*)d_in[4];
    const float* b0   = (const float*)d_in[5];
    const float* W1   = (const float*)d_in[6];
    const float* b1   = (const float*)d_in[7];
    const float* Wih  = (const float*)d_in[8];
    const float* Whh  = (const float*)d_in[9];
    const float* bih  = (const float*)d_in[10];
    const float* bhh  = (const float*)d_in[11];
    const float* Wout = (const float*)d_in[12];
    const float* bout = (const float*)d_in[13];
    float* out = (float*)d_out;

    char* ws = (char*)d_ws;
    size_t off = 0;
    __bf16* featb     = (__bf16*)(ws + off); off += (size_t)NN * 64 * 2;     // 12.8 MB
    int*    region    = (int*)(ws + off);    off += (size_t)BB * ECAP * 4;   // 5.0 MB
    int*    hist      = (int*)(ws + off);    off += (size_t)NB * BB * 4;     // 766 KB
    int*    blockBase = (int*)(ws + off);    off += (size_t)NB * BB * 4;     // 766 KB
    int*    bucketCnt = (int*)(ws + off);    off += (size_t)BB * 4;
    int*    cc        = (int*)(ws + off);    off += (size_t)NN * 4;
    __bf16* s1b       = (__bf16*)(ws + off); off += (size_t)NN * 64 * 2;     // 12.8 MB
    __bf16* s0b       = (__bf16*)(ws + off); off += (size_t)NN * 64 * 2;     // 12.8 MB
    __bf16* wb        = (__bf16*)(ws + off); off += 33792 * 2;
    int*    flag      = (int*)(ws + off);

    // 6628 = 1 detect + 132 weights + 6250 feat + 245 histogram blocks
    k_init<<<6628, 256, 0, stream>>>(etype, features, dst, W0, W1, Wih, Whh,
                                     Wout, featb, wb, hist, flag);
    k_s2<<<(BB + 3) / 4, 256, 0, stream>>>(hist, blockBase, bucketCnt);
    k_s3<<<NB, 512, 0, stream>>>(src, dst, etype, flag, blockBase, region);
    k_g2<<<BB, 512, 0, stream>>>(featb, region, bucketCnt, s1b, s0b, cc);
    k_m2<<<BB, 512, 0, stream>>>(s1b, s0b, featb, features, cc, wb,
                                 b0, b1, bih, bhh, bout, out);
}

// Round 14
// 170.202 us; speedup vs baseline: 1.0913x; 1.0913x over previous
//
#include <hip/hip_runtime.h>

// GGNN on MI355X. N=100000, E=1000000, H=M=64, C=16.
// R6: deterministic bucket sort (hist / scan / place / gather / MFMA GRU).
// R9/R10: GRU weights in LDS. R11: gather+MFMA fused. R15: fvv spill fix.
// R16/R17/R18: VALU cut neutral; LDS-atomic disaster; 4-edge unroll ->
//      172.7us total (BEST, measured R12-round).
// R19 post-mortem (split ablation): k_g2 at 4 blocks/CU ~34us == fused
//      gather at 2 blocks/CU. With R10 (2x residency -> +5%) this resolves
//      the pre-registered question: the gather is bounded by a per-CU
//      SHARED resource (L1 miss-handling / MSHR capacity on ~2M random
//      64B-line requests, ~3.7TB/s effective random LLC rate), not wave
//      concurrency. More waves / deeper ILP / issue restructuring cannot
//      move it; the access pattern has no exploitable locality (random
//      sources, reuse distance ~12.8MB). Split also cost +13us round-trip.
// R20: restore the measured best (R18) verbatim. Budget: 85.6us harness
//      fill (78% HBM peak, untouchable) + ~26us small kernels (BW/launch
//      floors) + 61us k_gm (~35us MSHR-bound gather, 5 failed attacks).
// ws: [featb | region 782*1600 | hist 245*782 | blockBase 245*782 |
//      bucketCnt 782 | wb | flag]

typedef __bf16 bf16x8 __attribute__((ext_vector_type(8)));
typedef float  f32x4  __attribute__((ext_vector_type(4)));
typedef int    i32x4  __attribute__((ext_vector_type(4)));

#define MFMA16 __builtin_amdgcn_mfma_f32_16x16x32_bf16
#define NN   100000
#define EE   1000000
#define BB   782     // buckets (dst >> 7)
#define NPB  128     // nodes per bucket
#define ECAP 1600    // bucket region capacity (mean 1280, +9 sigma)
#define DCAP 48      // per-node degree cap (Poisson(10), P(>=48) ~ 1e-17)
#define CSTRD 49     // CSR LDS stride (conflict pad)
#define NB   245     // histogram blocks (4096 edges each)
#define NWL  24576   // LDS-staged weights: wih (12288) + whh (12288)

__device__ __forceinline__ float sigmoidf_(float x) {
    return 1.0f / (1.0f + __expf(-x));
}

// swizzled LDS weight fragment read: e = element offset (16B-aligned).
__device__ __forceinline__ bf16x8 ldw(const __bf16* w, int e) {
    int bo = e * 2;
    bo ^= ((bo >> 7) & 7) << 4;
    return *(const bf16x8*)((const char*)w + bo);
}

// ---- fused init: dtype detect / weight cvt / feature cvt / dst histogram ----
__global__ __launch_bounds__(256) void k_init(const unsigned char* __restrict__ et,
                                              const float* __restrict__ feat,
                                              const int* __restrict__ dst,
                                              const float* __restrict__ w0,
                                              const float* __restrict__ w1,
                                              const float* __restrict__ wih,
                                              const float* __restrict__ whh,
                                              const float* __restrict__ wout,
                                              __bf16* __restrict__ featb,
                                              __bf16* __restrict__ wb,
                                              int* __restrict__ hist,
                                              int* __restrict__ flag) {
    int b = blockIdx.x, tid = threadIdx.x;
    if (b == 0) {
        // flag=1 iff any nonzero byte at offset%4!=0 in first 64KB (bool
        // storage); int32 0/1 storage has bytes 1..3 of every word zero.
        __shared__ int sdet[4];
        const i32x4* p = (const i32x4*)et + tid * 16;  // 256 B per thread
        unsigned acc = 0;
#pragma unroll
        for (int j = 0; j < 16; j++) {
            i32x4 w = p[j];
            acc |= (unsigned)(w[0] | w[1] | w[2] | w[3]) & 0xffffff00u;
        }
        unsigned long long m = __ballot(acc != 0);
        if ((tid & 63) == 0) sdet[tid >> 6] = (m != 0ULL);
        __syncthreads();
        if (tid == 0) *flag = sdet[0] | sdet[1] | sdet[2] | sdet[3];
        return;
    }
    if (b < 133) {  // 132 blocks * 256 = 33792 weights exactly
        int i = (b - 1) * 256 + tid;
        float v;
        if      (i < 4096)  v = w0[i];
        else if (i < 8192)  v = w1[i - 4096];
        else if (i < 20480) v = wih[i - 8192];
        else if (i < 32768) v = whh[i - 20480];
        else                v = wout[i - 32768];
        wb[i] = (__bf16)v;
        return;
    }
    if (b >= 6383) {  // fused k_s1: per-block dst-bucket histogram
        __shared__ int cnt[BB];
        int hb = b - 6383;
        for (int i = tid; i < BB; i += 256) cnt[i] = 0;
        __syncthreads();
        long e0 = (long)hb * 4096 + tid * 16;
#pragma unroll
        for (int g = 0; g < 2; g++) {
            long e = e0 + g * 8;
            if (e < EE) {
                i32x4 d0 = *(const i32x4*)(dst + e);
                i32x4 d1 = *(const i32x4*)(dst + e + 4);
#pragma unroll
                for (int j = 0; j < 4; j++) atomicAdd(&cnt[d0[j] >> 7], 1);
#pragma unroll
                for (int j = 0; j < 4; j++) atomicAdd(&cnt[d1[j] >> 7], 1);
            }
        }
        __syncthreads();
        for (int i = tid; i < BB; i += 256) hist[hb * BB + i] = cnt[i];
        return;
    }
    long i = ((long)(b - 133) * 256 + tid) * 4;
    if (i >= (long)NN * 64) return;
    f32x4 v = *(const f32x4*)(feat + i);
    union { __bf16 e[4]; unsigned long long u; } o;
#pragma unroll
    for (int j = 0; j < 4; j++) o.e[j] = (__bf16)v[j];
    *(unsigned long long*)(featb + i) = o.u;
}

// ---- s2: exclusive scan over blocks per bucket (1 wave/bucket) ----
__global__ __launch_bounds__(256) void k_s2(const int* __restrict__ hist,
                                            int* __restrict__ blockBase,
                                            int* __restrict__ bucketCnt) {
    int b = blockIdx.x * 4 + (threadIdx.x >> 6);
    int lane = threadIdx.x & 63;
    if (b >= BB) return;
    int carry = 0;
    for (int c = 0; c < 4; c++) {       // ceil(245/64) = 4 chunks
        int blk = c * 64 + lane;
        int v = (blk < NB) ? hist[blk * BB + b] : 0;
        int x = v;
#pragma unroll
        for (int off = 1; off < 64; off <<= 1) {
            int y = __shfl_up(x, off, 64);
            if (lane >= off) x += y;
        }
        if (blk < NB) blockBase[blk * BB + b] = x - v + carry;
        carry += __shfl(x, 63, 64);
    }
    if (lane == 0) bucketCnt[b] = carry;
}

// ---- s3: place edges deterministically (LDS cursors seeded w/ blockBase) ----
__global__ __launch_bounds__(512) void k_s3(const int* __restrict__ src,
                                            const int* __restrict__ dst,
                                            const unsigned char* __restrict__ etype,
                                            const int* __restrict__ flag,
                                            const int* __restrict__ blockBase,
                                            int* __restrict__ region) {
    __shared__ int cur[BB];
    int blk = blockIdx.x, tid = threadIdx.x;
    for (int i = tid; i < BB; i += 512) cur[i] = blockBase[blk * BB + i];
    __syncthreads();
    long e0 = (long)blk * 4096 + tid * 8;
    if (e0 >= EE) return;
    i32x4 s0 = *(const i32x4*)(src + e0);
    i32x4 s1 = *(const i32x4*)(src + e0 + 4);
    i32x4 d0 = *(const i32x4*)(dst + e0);
    i32x4 d1 = *(const i32x4*)(dst + e0 + 4);
    int t[8];
    if (*flag) {  // 1-byte bool storage
        unsigned long long w = *(const unsigned long long*)(etype + e0);
#pragma unroll
        for (int j = 0; j < 8; j++) t[j] = (int)((w >> (8 * j)) & 0xff);
    } else {      // int32 storage
        i32x4 w0 = *(const i32x4*)((const int*)etype + e0);
        i32x4 w1 = *(const i32x4*)((const int*)etype + e0 + 4);
#pragma unroll
        for (int j = 0; j < 4; j++) { t[j] = w0[j]; t[4 + j] = w1[j]; }
    }
    int dd[8] = {d0[0], d0[1], d0[2], d0[3], d1[0], d1[1], d1[2], d1[3]};
    int ss[8] = {s0[0], s0[1], s0[2], s0[3], s1[0], s1[1], s1[2], s1[3]};
#pragma unroll
    for (int j = 0; j < 8; j++) {
        int b  = dd[j] >> 7;
        int nl = dd[j] & 127;
        int r  = atomicAdd(&cur[b], 1);  // LDS returning atomic: fast
        if (r < ECAP)
            region[b * ECAP + r] = (nl << 18) | ((t[j] ? 1 : 0) << 17) | ss[j];
    }
}

// ---- fused gather + MFMA: CSR build -> 4-edge-unrolled gather -> agg MFMA
// -> GRU -> classifier. One bucket (128 nodes) per block.
__global__ __launch_bounds__(512)
__attribute__((amdgpu_waves_per_eu(4, 4)))
void k_gm(const __bf16* __restrict__ featb,
          const int* __restrict__ region,
          const int* __restrict__ bucketCnt,
          const float* __restrict__ feat,
          const __bf16* __restrict__ wb,
          const float* __restrict__ b0,
          const float* __restrict__ b1,
          const float* __restrict__ bih,
          const float* __restrict__ bhh,
          const float* __restrict__ bout,
          float* __restrict__ out) {
    // wlds: wih(0..12287)+whh(12288..24575), XOR-swizzled 16B blocks.
    // csr: per-node edge lists; wave w's 16-row chunk (3136B) is dead after
    // w's gather, then overlaid by w's sH (bf16 [16][80] = 2560B) — single-
    // wave in-order LDS makes this safe. Total 74.75KB -> 2 blocks/CU.
    __shared__ __align__(16) __bf16 wlds[NWL];
    __shared__ __align__(16) int csr[NPB * CSTRD];
    __shared__ int ncnt[NPB];
    int b = blockIdx.x, tid = threadIdx.x, lane = tid & 63, wave = tid >> 6;
    int L = lane & 15, q = lane >> 4;
    int n0 = b * NPB + wave * 16;   // NN%16==0: n0<NN => all 16 nodes valid

    int cntE = min(bucketCnt[b], ECAP);
    if (tid < NPB) ncnt[tid] = 0;
    __syncthreads();
    // CSR build + weight staging (independent streams, latencies interleave)
    const int* reg = region + b * ECAP;
    for (int i = tid; i < cntE; i += 512) {
        int rec = reg[i];
        int nl = rec >> 18;
        int r = atomicAdd(&ncnt[nl], 1);
        if (r < DCAP) csr[nl * CSTRD + r] = rec & 0x3ffff;  // type|src
    }
    const __bf16* wsrc = wb + 8192;  // wih | whh
    for (int k = tid * 8; k < NWL; k += 512 * 8) {
        bf16x8 v = *(const bf16x8*)(wsrc + k);
        int bo = k * 2;
        int so = bo ^ (((bo >> 7) & 7) << 4);
        *(bf16x8*)((char*)wlds + so) = v;
    }
    __syncthreads();

    // ---- gather: 8 waves x 16 nodes; lane (L,q) owns node n0+L dims
    // {q*8..q*8+7, 32+q*8..+7} — the MFMA A-fragment layout. 4-edge
    // unroll, 8 row loads in flight per trip; accumulation pair-granular
    // in index order -> bit-exact vs R15. ----
    int nl = wave * 16 + L;
    int cnt = (n0 < NN) ? min(ncnt[nl], DCAP) : 0;
    const int* eb = &csr[nl * CSTRD];

    float sA[16], s1[16];
#pragma unroll
    for (int j = 0; j < 16; j++) { sA[j] = 0.f; s1[j] = 0.f; }
    int c1 = 0;
    int i = 0;
    for (; i + 4 <= cnt; i += 4) {
        int e0v = eb[i], e1v = eb[i + 1], e2v = eb[i + 2], e3v = eb[i + 3];
        const __bf16* r0 = featb + (long)(e0v & 0x1ffff) * 64;
        const __bf16* r1 = featb + (long)(e1v & 0x1ffff) * 64;
        const __bf16* r2 = featb + (long)(e2v & 0x1ffff) * 64;
        const __bf16* r3 = featb + (long)(e3v & 0x1ffff) * 64;
        bf16x8 a0 = *(const bf16x8*)(r0 + q * 8);
        bf16x8 a1 = *(const bf16x8*)(r0 + 32 + q * 8);
        bf16x8 b0v = *(const bf16x8*)(r1 + q * 8);
        bf16x8 b1v = *(const bf16x8*)(r1 + 32 + q * 8);
        bf16x8 c0v = *(const bf16x8*)(r2 + q * 8);
        bf16x8 c1v = *(const bf16x8*)(r2 + 32 + q * 8);
        bf16x8 d0v = *(const bf16x8*)(r3 + q * 8);
        bf16x8 d1v = *(const bf16x8*)(r3 + 32 + q * 8);
        int t0 = (e0v >> 17) & 1, t1 = (e1v >> 17) & 1;
        int t2 = (e2v >> 17) & 1, t3 = (e3v >> 17) & 1;
        c1 += t0 + t1 + t2 + t3;
        float f0 = (float)t0, f1 = (float)t1, f2 = (float)t2, f3 = (float)t3;
#pragma unroll
        for (int j = 0; j < 8; j++) {
            float va = (float)a0[j], wa = (float)a1[j];
            float vb = (float)b0v[j], wb2 = (float)b1v[j];
            sA[j]     += va + vb;
            sA[8 + j] += wa + wb2;
            s1[j]     += f0 * va + f1 * vb;
            s1[8 + j] += f0 * wa + f1 * wb2;
            float vc = (float)c0v[j], wc = (float)c1v[j];
            float vd = (float)d0v[j], wd = (float)d1v[j];
            sA[j]     += vc + vd;
            sA[8 + j] += wc + wd;
            s1[j]     += f2 * vc + f3 * vd;
            s1[8 + j] += f2 * wc + f3 * wd;
        }
    }
    if (i + 2 <= cnt) {  // 2-edge tail (R15 body)
        int ea = eb[i], ebn = eb[i + 1];
        const __bf16* rowa = featb + (long)(ea & 0x1ffff) * 64;
        const __bf16* rowb = featb + (long)(ebn & 0x1ffff) * 64;
        bf16x8 a0 = *(const bf16x8*)(rowa + q * 8);
        bf16x8 a1 = *(const bf16x8*)(rowa + 32 + q * 8);
        bf16x8 b0v = *(const bf16x8*)(rowb + q * 8);
        bf16x8 b1v = *(const bf16x8*)(rowb + 32 + q * 8);
        int ta = (ea >> 17) & 1, tb = (ebn >> 17) & 1;
        c1 += ta + tb;
        float fa = (float)ta, fb = (float)tb;
#pragma unroll
        for (int j = 0; j < 8; j++) {
            float va = (float)a0[j], wa = (float)a1[j];
            float vb = (float)b0v[j], wb2 = (float)b1v[j];
            sA[j]     += va + vb;
            sA[8 + j] += wa + wb2;
            s1[j]     += fa * va + fb * vb;
            s1[8 + j] += fa * wa + fb * wb2;
        }
        i += 2;
    }
    if (i < cnt) {       // 1-edge tail (R15 body)
        int ea = eb[i];
        const __bf16* rowa = featb + (long)(ea & 0x1ffff) * 64;
        bf16x8 a0 = *(const bf16x8*)(rowa + q * 8);
        bf16x8 a1 = *(const bf16x8*)(rowa + 32 + q * 8);
        int ta = (ea >> 17) & 1;
        c1 += ta;
        float fa = (float)ta;
#pragma unroll
        for (int j = 0; j < 8; j++) {
            float va = (float)a0[j], wa = (float)a1[j];
            sA[j] += va;          sA[8 + j] += wa;
            s1[j] += fa * va;     s1[8 + j] += fa * wa;
        }
    }
    if (n0 >= NN) return;   // after last barrier: safe

    // Aft load (deferred: out of the gather loop's live range; L2-warm,
    // hides under the conversion + shuffle phase below)
    const __bf16* fr = featb + (long)(n0 + L) * 64;
    bf16x8 Aft[2] = { *(const bf16x8*)(fr + q * 8),
                      *(const bf16x8*)(fr + 32 + q * 8) };

    // ---- in-register A-fragment conversion (bit-identical to the old
    // s1b/s0b bf16 store + reload) ----
    bf16x8 AS1[2], AS0[2];
    {
        union { bf16x8 v; __bf16 e[8]; } u;
#pragma unroll
        for (int ch = 0; ch < 2; ch++) {
#pragma unroll
            for (int j = 0; j < 8; j++) u.e[j] = (__bf16)s1[ch * 8 + j];
            AS1[ch] = u.v;
#pragma unroll
            for (int j = 0; j < 8; j++) u.e[j] = (__bf16)(sA[ch * 8 + j] - s1[ch * 8 + j]);
            AS0[ch] = u.v;
        }
    }
    // counts exchange: every lane holds (cnt,c1) of node L; need node q*4+r
    int ccp = cnt | (c1 << 16);
    float fc1[4], fc0[4];
#pragma unroll
    for (int r = 0; r < 4; r++) {
        int v = __shfl(ccp, q * 4 + r, 64);
        int c1v = v >> 16;
        fc1[r] = (float)c1v; fc0[r] = (float)((v & 0xffff) - c1v);
    }

    // per-wave sH overlays this wave's own (dead) csr chunk
    __bf16* sH = (__bf16*)((char*)csr + wave * (16 * CSTRD * 4));
    const __bf16* w0b = wb, * w1b = wb + 4096, * woutb = wb + 32768;
    f32x4 zz = {0.f, 0.f, 0.f, 0.f};

    // agg = S1@W0^T + S0@W1^T + per-count biases (B frags global, L2-hit)
#pragma unroll
    for (int nb = 0; nb < 4; nb++) {
        f32x4 acc = zz;
#pragma unroll
        for (int ch = 0; ch < 2; ch++) {
            int off = (nb * 16 + L) * 64 + ch * 32 + q * 8;
            acc = MFMA16(AS1[ch], *(const bf16x8*)(w0b + off), acc, 0, 0, 0);
            acc = MFMA16(AS0[ch], *(const bf16x8*)(w1b + off), acc, 0, 0, 0);
        }
        float bs0 = b0[nb * 16 + L], bs1 = b1[nb * 16 + L];
#pragma unroll
        for (int r = 0; r < 4; r++)
            sH[(q * 4 + r) * 80 + nb * 16 + L] =
                (__bf16)(acc[r] + fc1[r] * bs0 + fc0[r] * bs1);
    }

    // D->A transpose read (agg region of sH dead after this)
    bf16x8 Aag[2];
#pragma unroll
    for (int ch = 0; ch < 2; ch++)
        Aag[ch] = *(const bf16x8*)&sH[L * 80 + ch * 32 + q * 8];

    // GRU gates [r,z,n]; B fragments from LDS (wih @0, whh @12288).
    // feat fp32 blend values loaded per-nb (4-reg live range, R15).
#pragma unroll
    for (int nb = 0; nb < 4; nb++) {
        int row = nb * 16 + L;
        float fvb[4];
#pragma unroll
        for (int r = 0; r < 4; r++)
            fvb[r] = feat[(long)(n0 + q * 4 + r) * 64 + nb * 16 + L];
        f32x4 aR = zz, aZ = zz, aIN = zz, aHN = zz;
#pragma unroll
        for (int ch = 0; ch < 2; ch++) {
            int ko = ch * 32 + q * 8;
            aR  = MFMA16(Aag[ch], ldw(wlds, row * 64 + ko), aR, 0, 0, 0);
            aR  = MFMA16(Aft[ch], ldw(wlds, 12288 + row * 64 + ko), aR, 0, 0, 0);
            aZ  = MFMA16(Aag[ch], ldw(wlds, (64 + row) * 64 + ko), aZ, 0, 0, 0);
            aZ  = MFMA16(Aft[ch], ldw(wlds, 12288 + (64 + row) * 64 + ko), aZ, 0, 0, 0);
            aIN = MFMA16(Aag[ch], ldw(wlds, (128 + row) * 64 + ko), aIN, 0, 0, 0);
            aHN = MFMA16(Aft[ch], ldw(wlds, 12288 + (128 + row) * 64 + ko), aHN, 0, 0, 0);
        }
        int h = row;
        float br  = bih[h] + bhh[h];
        float bz  = bih[64 + h] + bhh[64 + h];
        float bin = bih[128 + h];
        float bhn = bhh[128 + h];
#pragma unroll
        for (int r = 0; r < 4; r++) {
            float rv = sigmoidf_(aR[r] + br);
            float zv = sigmoidf_(aZ[r] + bz);
            float nv = tanhf(aIN[r] + bin + rv * (aHN[r] + bhn));
            float fv = fvb[r];  // fp32 blend for accuracy
            sH[(q * 4 + r) * 80 + h] = (__bf16)((1.0f - zv) * nv + zv * fv);
        }
    }

    // out = h @ W_out^T + b_out (wout global, L2-hit; store coalesced:
    // per-r instruction fills 4 full 64B lines)
    bf16x8 Ah0 = *(const bf16x8*)&sH[L * 80 + q * 8];
    bf16x8 Ah1 = *(const bf16x8*)&sH[L * 80 + 32 + q * 8];
    bf16x8 Bo0 = *(const bf16x8*)(woutb + L * 64 + q * 8);
    bf16x8 Bo1 = *(const bf16x8*)(woutb + L * 64 + 32 + q * 8);
    f32x4 o = zz;
    o = MFMA16(Ah0, Bo0, o, 0, 0, 0);
    o = MFMA16(Ah1, Bo1, o, 0, 0, 0);
    float bo = bout[L];
#pragma unroll
    for (int r = 0; r < 4; r++)
        out[(long)(n0 + q * 4 + r) * 16 + L] = o[r] + bo;
}

extern "C" void kernel_launch(void* const* d_in, const int* in_sizes, int n_in,
                              void* d_out, int out_size, void* d_ws, size_t ws_size,
                              hipStream_t stream) {
    const float* features = (const float*)d_in[0];
    const int*   src      = (const int*)d_in[1];
    const int*   dst      = (const int*)d_in[2];
    const unsigned char* etype = (const unsigned char*)d_in[3];
    const float* W0   = (const float*)d_in[4];
    const float* b0   = (const float*)d_in[5];
    const float* W1   = (const float*)d_in[6];
    const float* b1   = (const float*)d_in[7];
    const float* Wih  = (const float*)d_in[8];
    const float* Whh  = (const float*)d_in[9];
    const float* bih  = (const float*)d_in[10];
    const float* bhh  = (const float*)d_in[11];
    const float* Wout = (const float*)d_in[12];
    const float* bout = (const float*)d_in[13];
    float* out = (float*)d_out;

    char* ws = (char*)d_ws;
    size_t off = 0;
    __bf16* featb     = (__bf16*)(ws + off); off += (size_t)NN * 64 * 2;     // 12.8 MB
    int*    region    = (int*)(ws + off);    off += (size_t)BB * ECAP * 4;   // 5.0 MB
    int*    hist      = (int*)(ws + off);    off += (size_t)NB * BB * 4;     // 766 KB
    int*    blockBase = (int*)(ws + off);    off += (size_t)NB * BB * 4;     // 766 KB
    int*    bucketCnt = (int*)(ws + off);    off += (size_t)BB * 4;
    __bf16* wb        = (__bf16*)(ws + off); off += 33792 * 2;
    int*    flag      = (int*)(ws + off);

    // 6628 = 1 detect + 132 weights + 6250 feat + 245 histogram blocks
    k_init<<<6628, 256, 0, stream>>>(etype, features, dst, W0, W1, Wih, Whh,
                                     Wout, featb, wb, hist, flag);
    k_s2<<<(BB + 3) / 4, 256, 0, stream>>>(hist, blockBase, bucketCnt);
    k_s3<<<NB, 512, 0, stream>>>(src, dst, etype, flag, blockBase, region);
    // fused gather + MFMA: one bucket (128 nodes) per block
    k_gm<<<BB, 512, 0, stream>>>(featb, region, bucketCnt, features, wb,
                                 b0, b1, bih, bhh, bout, out);
}